// Round 7
// baseline (1207.065 us; speedup 1.0000x reference)
//
#include <hip/hip_runtime.h>
#include <hip/hip_bf16.h>

#define HIDDEN 64
#define TN 64             // nodes per tile
#define MPAD 68           // mean-tile row stride: +4 banks/row -> conflict-free b128 reads
#define SRCM 0x01FFFFFF   // low 25 bits of packed csr entry = src id

// ---------------------------------------------------------------------------
// CSR build step 1: degree histogram over dst
// ---------------------------------------------------------------------------
__global__ __launch_bounds__(256) void k_hist(
    const int* __restrict__ ei, int* __restrict__ deg, int nEdges)
{
    for (int e = blockIdx.x * blockDim.x + threadIdx.x; e < nEdges;
         e += gridDim.x * blockDim.x) {
        atomicAdd(&deg[ei[nEdges + e]], 1);
    }
}

// ---------------------------------------------------------------------------
// Two-level parallel exclusive scan
// ---------------------------------------------------------------------------
__global__ __launch_bounds__(256) void k_scan1(
    const int* __restrict__ deg, int* __restrict__ rowPtr,
    int* __restrict__ blockSum, int n)
{
    __shared__ int tmp[256];
    const int t = threadIdx.x;
    const int i = blockIdx.x * 256 + t;
    const int v = (i < n) ? deg[i] : 0;
    tmp[t] = v;
    __syncthreads();
#pragma unroll
    for (int off = 1; off < 256; off <<= 1) {
        const int u = (t >= off) ? tmp[t - off] : 0;
        __syncthreads();
        tmp[t] += u;
        __syncthreads();
    }
    if (i < n) rowPtr[i] = tmp[t] - v;
    if (t == 255) blockSum[blockIdx.x] = tmp[255];
}

__global__ __launch_bounds__(512) void k_scan2(
    int* __restrict__ blockSum, int* __restrict__ rowPtr, int nb, int n)
{
    __shared__ int tmp[512];
    const int t = threadIdx.x;
    const int v = (t < nb) ? blockSum[t] : 0;
    tmp[t] = v;
    __syncthreads();
#pragma unroll
    for (int off = 1; off < 512; off <<= 1) {
        const int u = (t >= off) ? tmp[t - off] : 0;
        __syncthreads();
        tmp[t] += u;
        __syncthreads();
    }
    if (t < nb) blockSum[t] = tmp[t] - v;
    if (t == nb - 1) rowPtr[n] = tmp[t];
}

__global__ __launch_bounds__(256) void k_scan3(
    int* __restrict__ rowPtr, int* __restrict__ cursor,
    const int* __restrict__ blockSum, int n)
{
    const int i = blockIdx.x * 256 + threadIdx.x;
    if (i < n) {
        const int v = rowPtr[i] + blockSum[blockIdx.x];
        rowPtr[i] = v;
        cursor[i] = v;
    }
}

// ---------------------------------------------------------------------------
// CSR fill: pack src (25 bits) | dstLocal=dst&63 (bits 25..30). src<2^17 fits.
// ---------------------------------------------------------------------------
__global__ __launch_bounds__(256) void k_fill(
    const int* __restrict__ ei, int* __restrict__ cursor,
    int* __restrict__ csrSrc, int nEdges)
{
    for (int e = blockIdx.x * blockDim.x + threadIdx.x; e < nEdges;
         e += gridDim.x * blockDim.x) {
        const int dst = ei[nEdges + e];
        const int pos = atomicAdd(&cursor[dst], 1);
        csrSrc[pos] = ei[e] | ((dst & 63) << 25);
    }
}

// ---------------------------------------------------------------------------
// Fused SAGE layer, edge-parallel gather version.
// 512 threads = 8 waves. Per 64-node tile:
//   phase 1: zero sM; stage [Wl;Wr]; sInv
//   phase 2: edge-parallel: lane=feature; per edge atomicAdd into sM[dstLocal]
//            (8 independent row-gathers in flight per wave -> max MLP)
//   phase 3: sM /= deg
//   phase 4: split-K GEMM: team0 (tid<256): sM @ Wl; team1: x_root @ Wr + bias
//            (team1 reads root rows from global: L1-broadcast, saves LDS)
//   phase 5: team1 parks acc in sM-as-sC; team0 adds, ReLU?, stores.
// LDS = 17408 + 32768 + 256 = 50.4 KB -> 3 blocks/CU = 24 waves/CU.
// ---------------------------------------------------------------------------
template <bool RELU>
__global__ __launch_bounds__(512, 6) void k_fused(
    const float* __restrict__ xin,     // [N,64]
    const int* __restrict__ rowPtr,    // [N+1]
    const int* __restrict__ csrSrc,    // [E] packed
    const float* __restrict__ Wl,      // [64,64]
    const float* __restrict__ bl,      // [64]
    const float* __restrict__ Wr,      // [64,64]
    float* __restrict__ outp,          // [N,64]
    int nNodes)
{
    __shared__ __align__(16) float sM[TN][MPAD];          // mean sums, later sC
    __shared__ __align__(16) float sB[2 * HIDDEN][HIDDEN]; // [Wl;Wr]
    __shared__ float sInv[TN];

    const int tid  = threadIdx.x;
    const int w    = tid >> 6;
    const int lane = tid & 63;
    const int base = blockIdx.x * TN;

    // ---- phase 1: staging ----
    for (int i = tid; i < HIDDEN * HIDDEN; i += 512) {
        sB[i >> 6][i & 63]          = Wl[i];
        sB[(i >> 6) + HIDDEN][i & 63] = Wr[i];
    }
    for (int idx = tid; idx < TN * 16; idx += 512)
        *(float4*)&sM[idx >> 4][(idx & 15) * 4] = make_float4(0.f, 0.f, 0.f, 0.f);
    if (tid < TN) {
        const int g = base + tid;
        float iv = 1.f;
        if (g < nNodes) {
            const int d = rowPtr[g + 1] - rowPtr[g];
            if (d > 0) iv = 1.f / (float)d;
        }
        sInv[tid] = iv;
    }
    __syncthreads();

    // ---- phase 2: edge-parallel gather + LDS atomic accumulate ----
    {
        const int eBeg = rowPtr[base];
        const int eEnd = rowPtr[min(base + TN, nNodes)];
        int e = eBeg + w * 8;
#pragma unroll 1
        for (; e + 8 <= eEnd; e += 64) {          // 8 waves x 8-edge groups
            int   pk[8];
            float v[8];
#pragma unroll
            for (int k = 0; k < 8; ++k) pk[k] = csrSrc[e + k];
#pragma unroll
            for (int k = 0; k < 8; ++k)
                v[k] = xin[(pk[k] & SRCM) * HIDDEN + lane];   // 8 in flight
#pragma unroll
            for (int k = 0; k < 8; ++k)
                atomicAdd(&sM[pk[k] >> 25][lane], v[k]);      // ds_add_f32
        }
        if (e < eEnd) {                            // single partial tail group
#pragma unroll 1
            for (; e < eEnd; ++e) {
                const int p = csrSrc[e];
                atomicAdd(&sM[p >> 25][lane], xin[(p & SRCM) * HIDDEN + lane]);
            }
        }
    }
    __syncthreads();

    // ---- phase 3: divide by degree ----
    for (int idx = tid; idx < TN * 16; idx += 512) {
        const int row = idx >> 4, c4 = (idx & 15) * 4;
        float4 v = *(const float4*)&sM[row][c4];
        const float iv = sInv[row];
        v.x *= iv; v.y *= iv; v.z *= iv; v.w *= iv;
        *(float4*)&sM[row][c4] = v;
    }
    __syncthreads();

    // ---- phase 4: split-K GEMM ----
    const int team = tid >> 8;        // 0: mean@Wl, 1: root@Wr + bias
    const int tt   = tid & 255;
    const int tr   = tt >> 4;         // 0..15 row group (4 nodes)
    const int tc   = tt & 15;         // 0..15 col group (4 cols)
    float acc[4][4];

    if (team == 0) {
#pragma unroll
        for (int r = 0; r < 4; ++r)
#pragma unroll
            for (int j = 0; j < 4; ++j) acc[r][j] = 0.f;
#pragma unroll
        for (int k4 = 0; k4 < 16; ++k4) {
            float4 A4[4], B4[4];
#pragma unroll
            for (int r = 0; r < 4; ++r)
                A4[r] = *(const float4*)&sM[tr * 4 + r][k4 * 4];
#pragma unroll
            for (int kk = 0; kk < 4; ++kk)
                B4[kk] = *(const float4*)&sB[k4 * 4 + kk][tc * 4];
#pragma unroll
            for (int r = 0; r < 4; ++r) {
                acc[r][0] = fmaf(A4[r].x, B4[0].x, acc[r][0]);
                acc[r][1] = fmaf(A4[r].x, B4[0].y, acc[r][1]);
                acc[r][2] = fmaf(A4[r].x, B4[0].z, acc[r][2]);
                acc[r][3] = fmaf(A4[r].x, B4[0].w, acc[r][3]);
                acc[r][0] = fmaf(A4[r].y, B4[1].x, acc[r][0]);
                acc[r][1] = fmaf(A4[r].y, B4[1].y, acc[r][1]);
                acc[r][2] = fmaf(A4[r].y, B4[1].z, acc[r][2]);
                acc[r][3] = fmaf(A4[r].y, B4[1].w, acc[r][3]);
                acc[r][0] = fmaf(A4[r].z, B4[2].x, acc[r][0]);
                acc[r][1] = fmaf(A4[r].z, B4[2].y, acc[r][1]);
                acc[r][2] = fmaf(A4[r].z, B4[2].z, acc[r][2]);
                acc[r][3] = fmaf(A4[r].z, B4[2].w, acc[r][3]);
                acc[r][0] = fmaf(A4[r].w, B4[3].x, acc[r][0]);
                acc[r][1] = fmaf(A4[r].w, B4[3].y, acc[r][1]);
                acc[r][2] = fmaf(A4[r].w, B4[3].z, acc[r][2]);
                acc[r][3] = fmaf(A4[r].w, B4[3].w, acc[r][3]);
            }
        }
    } else {
        const float* xr[4];
#pragma unroll
        for (int r = 0; r < 4; ++r) {
            int g = base + tr * 4 + r;
            g = (g < nNodes) ? g : 0;              // clamp; result never stored
            xr[r] = xin + g * HIDDEN;
        }
#pragma unroll
        for (int r = 0; r < 4; ++r)
#pragma unroll
            for (int j = 0; j < 4; ++j) acc[r][j] = bl[tc * 4 + j];
#pragma unroll
        for (int k4 = 0; k4 < 16; ++k4) {
            float4 A4[4], B4[4];
#pragma unroll
            for (int r = 0; r < 4; ++r)
                A4[r] = *(const float4*)(xr[r] + k4 * 4);   // L1-broadcast
#pragma unroll
            for (int kk = 0; kk < 4; ++kk)
                B4[kk] = *(const float4*)&sB[HIDDEN + k4 * 4 + kk][tc * 4];
#pragma unroll
            for (int r = 0; r < 4; ++r) {
                acc[r][0] = fmaf(A4[r].x, B4[0].x, acc[r][0]);
                acc[r][1] = fmaf(A4[r].x, B4[0].y, acc[r][1]);
                acc[r][2] = fmaf(A4[r].x, B4[0].z, acc[r][2]);
                acc[r][3] = fmaf(A4[r].x, B4[0].w, acc[r][3]);
                acc[r][0] = fmaf(A4[r].y, B4[1].x, acc[r][0]);
                acc[r][1] = fmaf(A4[r].y, B4[1].y, acc[r][1]);
                acc[r][2] = fmaf(A4[r].y, B4[1].z, acc[r][2]);
                acc[r][3] = fmaf(A4[r].y, B4[1].w, acc[r][3]);
                acc[r][0] = fmaf(A4[r].z, B4[2].x, acc[r][0]);
                acc[r][1] = fmaf(A4[r].z, B4[2].y, acc[r][1]);
                acc[r][2] = fmaf(A4[r].z, B4[2].z, acc[r][2]);
                acc[r][3] = fmaf(A4[r].z, B4[2].w, acc[r][3]);
                acc[r][0] = fmaf(A4[r].w, B4[3].x, acc[r][0]);
                acc[r][1] = fmaf(A4[r].w, B4[3].y, acc[r][1]);
                acc[r][2] = fmaf(A4[r].w, B4[3].z, acc[r][2]);
                acc[r][3] = fmaf(A4[r].w, B4[3].w, acc[r][3]);
            }
        }
    }
    __syncthreads();          // team0 done reading sM; safe to repurpose as sC

    // ---- phase 5: combine ----
    if (team == 1) {
#pragma unroll
        for (int r = 0; r < 4; ++r) {
            float4 st;
            st.x = acc[r][0]; st.y = acc[r][1];
            st.z = acc[r][2]; st.w = acc[r][3];
            *(float4*)&sM[tr * 4 + r][tc * 4] = st;
        }
    }
    __syncthreads();
    if (team == 0) {
#pragma unroll
        for (int r = 0; r < 4; ++r) {
            const int g = base + tr * 4 + r;
            if (g < nNodes) {
                const float4 c4 = *(const float4*)&sM[tr * 4 + r][tc * 4];
                float4 o;
                o.x = acc[r][0] + c4.x; o.y = acc[r][1] + c4.y;
                o.z = acc[r][2] + c4.z; o.w = acc[r][3] + c4.w;
                if (RELU) {
                    o.x = fmaxf(o.x, 0.f); o.y = fmaxf(o.y, 0.f);
                    o.z = fmaxf(o.z, 0.f); o.w = fmaxf(o.w, 0.f);
                }
                *(float4*)&outp[g * HIDDEN + tc * 4] = o;
            }
        }
    }
}

extern "C" void kernel_launch(void* const* d_in, const int* in_sizes, int n_in,
                              void* d_out, int out_size, void* d_ws, size_t ws_size,
                              hipStream_t stream)
{
    const float* x   = (const float*)d_in[0];
    const int*   ei  = (const int*)d_in[1];   // [2,E]
    const float* W1l = (const float*)d_in[2];
    const float* b1l = (const float*)d_in[3];
    const float* W1r = (const float*)d_in[4];
    const float* W2l = (const float*)d_in[5];
    const float* b2l = (const float*)d_in[6];
    const float* W2r = (const float*)d_in[7];
    float* out = (float*)d_out;

    const int nNodes = in_sizes[0] / HIDDEN;   // 100000
    const int nEdges = in_sizes[1] / 2;        // 1250000

    // workspace: h [N*64] | deg [N+1] | rowPtr [N+1] | cursor [N] | csrSrc [E]
    //            | blockSum [512]
    float* h        = (float*)d_ws;
    int*   deg      = (int*)(h + (size_t)nNodes * HIDDEN);
    int*   rowPtr   = deg + (nNodes + 1);
    int*   cursor   = rowPtr + (nNodes + 1);
    int*   csrSrc   = cursor + nNodes;
    int*   blockSum = csrSrc + nEdges;

    const int nTiles  = (nNodes + TN - 1) / TN;
    const int nChunks = (nNodes + 255) / 256;

    // ---- CSR build (shared by both layers) ----
    hipMemsetAsync(deg, 0, (size_t)(nNodes + 1) * sizeof(int), stream);
    k_hist<<<2048, 256, 0, stream>>>(ei, deg, nEdges);
    k_scan1<<<nChunks, 256, 0, stream>>>(deg, rowPtr, blockSum, nNodes);
    k_scan2<<<1, 512, 0, stream>>>(blockSum, rowPtr, nChunks, nNodes);
    k_scan3<<<nChunks, 256, 0, stream>>>(rowPtr, cursor, blockSum, nNodes);
    k_fill<<<2048, 256, 0, stream>>>(ei, cursor, csrSrc, nEdges);

    // ---- layer 1: h = relu(mean(x) @ W1l + b1l + x @ W1r) ----
    k_fused<true><<<nTiles, 512, 0, stream>>>(x, rowPtr, csrSrc, W1l, b1l, W1r,
                                              h, nNodes);
    // ---- layer 2: out = mean(h) @ W2l + b2l + h @ W2r ----
    k_fused<false><<<nTiles, 512, 0, stream>>>(h, rowPtr, csrSrc, W2l, b2l, W2r,
                                               out, nNodes);
}

// Round 9
// 1205.237 us; speedup vs baseline: 1.0015x; 1.0015x over previous
//
#include <hip/hip_runtime.h>
#include <hip/hip_bf16.h>

#define HIDDEN 64
#define TN 64             // nodes per tile
#define MPAD 68           // mean-tile row stride (float units)
#define SRCM 0x01FFFFFF   // low 25 bits of packed csr entry = src id

static __device__ __forceinline__ unsigned short f2bf(float f) {
    unsigned int u = __float_as_uint(f);
    u += 0x7FFF + ((u >> 16) & 1);        // round-to-nearest-even
    return (unsigned short)(u >> 16);
}
static __device__ __forceinline__ float bf2f(unsigned short s) {
    return __uint_as_float((unsigned int)s << 16);
}

// ---------------------------------------------------------------------------
// CSR build step 1: degree histogram over dst
// ---------------------------------------------------------------------------
__global__ __launch_bounds__(256) void k_hist(
    const int* __restrict__ ei, int* __restrict__ deg, int nEdges)
{
    for (int e = blockIdx.x * blockDim.x + threadIdx.x; e < nEdges;
         e += gridDim.x * blockDim.x) {
        atomicAdd(&deg[ei[nEdges + e]], 1);
    }
}

// ---------------------------------------------------------------------------
// Two-level parallel exclusive scan
// ---------------------------------------------------------------------------
__global__ __launch_bounds__(256) void k_scan1(
    const int* __restrict__ deg, int* __restrict__ rowPtr,
    int* __restrict__ blockSum, int n)
{
    __shared__ int tmp[256];
    const int t = threadIdx.x;
    const int i = blockIdx.x * 256 + t;
    const int v = (i < n) ? deg[i] : 0;
    tmp[t] = v;
    __syncthreads();
#pragma unroll
    for (int off = 1; off < 256; off <<= 1) {
        const int u = (t >= off) ? tmp[t - off] : 0;
        __syncthreads();
        tmp[t] += u;
        __syncthreads();
    }
    if (i < n) rowPtr[i] = tmp[t] - v;
    if (t == 255) blockSum[blockIdx.x] = tmp[255];
}

__global__ __launch_bounds__(512) void k_scan2(
    int* __restrict__ blockSum, int* __restrict__ rowPtr, int nb, int n)
{
    __shared__ int tmp[512];
    const int t = threadIdx.x;
    const int v = (t < nb) ? blockSum[t] : 0;
    tmp[t] = v;
    __syncthreads();
#pragma unroll
    for (int off = 1; off < 512; off <<= 1) {
        const int u = (t >= off) ? tmp[t - off] : 0;
        __syncthreads();
        tmp[t] += u;
        __syncthreads();
    }
    if (t < nb) blockSum[t] = tmp[t] - v;
    if (t == nb - 1) rowPtr[n] = tmp[t];
}

__global__ __launch_bounds__(256) void k_scan3(
    int* __restrict__ rowPtr, int* __restrict__ cursor,
    const int* __restrict__ blockSum, int n)
{
    const int i = blockIdx.x * 256 + threadIdx.x;
    if (i < n) {
        const int v = rowPtr[i] + blockSum[blockIdx.x];
        rowPtr[i] = v;
        cursor[i] = v;
    }
}

// ---------------------------------------------------------------------------
// CSR fill: pack src (25 bits) | dstLocal=dst&63 (bits 25..30)
// ---------------------------------------------------------------------------
__global__ __launch_bounds__(256) void k_fill(
    const int* __restrict__ ei, int* __restrict__ cursor,
    int* __restrict__ csrSrc, int nEdges)
{
    for (int e = blockIdx.x * blockDim.x + threadIdx.x; e < nEdges;
         e += gridDim.x * blockDim.x) {
        const int dst = ei[nEdges + e];
        const int pos = atomicAdd(&cursor[dst], 1);
        csrSrc[pos] = ei[e] | ((dst & 63) << 25);
    }
}

// ---------------------------------------------------------------------------
// fp32 -> bf16 conversion (layer-1 gather table), 8 elems/thread
// ---------------------------------------------------------------------------
__global__ __launch_bounds__(256) void k_tobf16(
    const float* __restrict__ src, unsigned short* __restrict__ dst, int n8)
{
    for (int i = blockIdx.x * 256 + threadIdx.x; i < n8; i += gridDim.x * 256) {
        const float4 a = ((const float4*)src)[2 * i];
        const float4 b = ((const float4*)src)[2 * i + 1];
        uint4 o;
        o.x = (unsigned)f2bf(a.x) | ((unsigned)f2bf(a.y) << 16);
        o.y = (unsigned)f2bf(a.z) | ((unsigned)f2bf(a.w) << 16);
        o.z = (unsigned)f2bf(b.x) | ((unsigned)f2bf(b.y) << 16);
        o.w = (unsigned)f2bf(b.z) | ((unsigned)f2bf(b.w) << 16);
        ((uint4*)dst)[i] = o;
    }
}

// ---------------------------------------------------------------------------
// Fused SAGE layer, bf16 edge-parallel gather.
// 512 threads = 8 waves. Phase 2: lane covers a FEATURE-PAIR of one of two
// edges (half = lane>>5): 8 uint loads -> 16 edges in flight per wave.
// fp32 LDS-atomic accumulate; fp32 GEMM.
//  OUT_BF16:  epilogue writes bf16 into goutb (layer 1 -> layer-2 table)
//  ROOT_BF16: root path reads bf16 rootb (layer 2) instead of fp32 rootf
// LDS = 17408 + 32768 + 256 = 50.4 KB -> 3 blocks/CU.
// ---------------------------------------------------------------------------
template <bool RELU, bool OUT_BF16, bool ROOT_BF16>
__global__ __launch_bounds__(512, 6) void k_fused(
    const unsigned short* __restrict__ gtab,   // [N,64] bf16 gather table
    const float* __restrict__ rootf,           // [N,64] f32 root (or null)
    const unsigned short* __restrict__ rootb,  // [N,64] bf16 root (or null)
    const int* __restrict__ rowPtr,            // [N+1]
    const int* __restrict__ csrSrc,            // [E] packed
    const float* __restrict__ Wl,              // [64,64]
    const float* __restrict__ bl,              // [64]
    const float* __restrict__ Wr,              // [64,64]
    float* __restrict__ outp,                  // [N,64] f32 out (or null)
    unsigned short* __restrict__ goutb,        // [N,64] bf16 out (or null)
    int nNodes)
{
    __shared__ __align__(16) float sM[TN][MPAD];           // sums, later sC
    __shared__ __align__(16) float sB[2 * HIDDEN][HIDDEN]; // [Wl;Wr]
    __shared__ float sInv[TN];

    const int tid  = threadIdx.x;
    const int w    = tid >> 6;
    const int lane = tid & 63;
    const int base = blockIdx.x * TN;

    // ---- phase 1: staging ----
    for (int i = tid; i < HIDDEN * HIDDEN; i += 512) {
        sB[i >> 6][i & 63]            = Wl[i];
        sB[(i >> 6) + HIDDEN][i & 63] = Wr[i];
    }
    for (int idx = tid; idx < TN * 16; idx += 512)
        *(float4*)&sM[idx >> 4][(idx & 15) * 4] = make_float4(0.f, 0.f, 0.f, 0.f);
    if (tid < TN) {
        const int g = base + tid;
        float iv = 1.f;
        if (g < nNodes) {
            const int d = rowPtr[g + 1] - rowPtr[g];
            if (d > 0) iv = 1.f / (float)d;
        }
        sInv[tid] = iv;
    }
    __syncthreads();

    // ---- phase 2: bf16 edge-parallel gather + fp32 LDS atomic accumulate ----
    {
        const int eBeg = rowPtr[base];
        const int eEnd = rowPtr[min(base + TN, nNodes)];
        const int half = lane >> 5;          // which edge of each pair
        const int f2   = (lane & 31) * 2;    // feature pair base
        int e = eBeg + w * 16;
#pragma unroll 1
        for (; e + 16 <= eEnd; e += 128) {   // 8 waves x 16 edges
            int pk[8];
            unsigned int val[8];
#pragma unroll
            for (int p = 0; p < 8; ++p)
                pk[p] = csrSrc[e + 2 * p + half];
#pragma unroll
            for (int p = 0; p < 8; ++p)      // 8 loads = 16 edges in flight
                val[p] = *(const unsigned int*)&gtab[(pk[p] & SRCM) * HIDDEN + f2];
#pragma unroll
            for (int p = 0; p < 8; ++p) {
                atomicAdd(&sM[pk[p] >> 25][f2],     __uint_as_float(val[p] << 16));
                atomicAdd(&sM[pk[p] >> 25][f2 + 1], __uint_as_float(val[p] & 0xFFFF0000u));
            }
        }
        if (e < eEnd) {                      // at most one wave (window 15 < stride 16)
#pragma unroll 1
            for (; e < eEnd; ++e) {
                const int pk = csrSrc[e];
                const unsigned short u = gtab[(pk & SRCM) * HIDDEN + lane];
                atomicAdd(&sM[pk >> 25][lane], bf2f(u));
            }
        }
    }
    __syncthreads();

    // ---- phase 3: divide by degree ----
    for (int idx = tid; idx < TN * 16; idx += 512) {
        const int row = idx >> 4, c4 = (idx & 15) * 4;
        float4 v = *(const float4*)&sM[row][c4];
        const float iv = sInv[row];
        v.x *= iv; v.y *= iv; v.z *= iv; v.w *= iv;
        *(float4*)&sM[row][c4] = v;
    }
    __syncthreads();

    // ---- phase 4: split-K GEMM ----
    const int team = tid >> 8;        // 0: mean@Wl, 1: root@Wr + bias
    const int tt   = tid & 255;
    const int tr   = tt >> 4;
    const int tc   = tt & 15;
    float acc[4][4];

    if (team == 0) {
#pragma unroll
        for (int r = 0; r < 4; ++r)
#pragma unroll
            for (int j = 0; j < 4; ++j) acc[r][j] = 0.f;
#pragma unroll
        for (int k4 = 0; k4 < 16; ++k4) {
            float4 A4[4], B4[4];
#pragma unroll
            for (int r = 0; r < 4; ++r)
                A4[r] = *(const float4*)&sM[tr * 4 + r][k4 * 4];
#pragma unroll
            for (int kk = 0; kk < 4; ++kk)
                B4[kk] = *(const float4*)&sB[k4 * 4 + kk][tc * 4];
#pragma unroll
            for (int r = 0; r < 4; ++r) {
                acc[r][0] = fmaf(A4[r].x, B4[0].x, acc[r][0]);
                acc[r][1] = fmaf(A4[r].x, B4[0].y, acc[r][1]);
                acc[r][2] = fmaf(A4[r].x, B4[0].z, acc[r][2]);
                acc[r][3] = fmaf(A4[r].x, B4[0].w, acc[r][3]);
                acc[r][0] = fmaf(A4[r].y, B4[1].x, acc[r][0]);
                acc[r][1] = fmaf(A4[r].y, B4[1].y, acc[r][1]);
                acc[r][2] = fmaf(A4[r].y, B4[1].z, acc[r][2]);
                acc[r][3] = fmaf(A4[r].y, B4[1].w, acc[r][3]);
                acc[r][0] = fmaf(A4[r].z, B4[2].x, acc[r][0]);
                acc[r][1] = fmaf(A4[r].z, B4[2].y, acc[r][1]);
                acc[r][2] = fmaf(A4[r].z, B4[2].z, acc[r][2]);
                acc[r][3] = fmaf(A4[r].z, B4[2].w, acc[r][3]);
                acc[r][0] = fmaf(A4[r].w, B4[3].x, acc[r][0]);
                acc[r][1] = fmaf(A4[r].w, B4[3].y, acc[r][1]);
                acc[r][2] = fmaf(A4[r].w, B4[3].z, acc[r][2]);
                acc[r][3] = fmaf(A4[r].w, B4[3].w, acc[r][3]);
            }
        }
    } else {
#pragma unroll
        for (int r = 0; r < 4; ++r)
#pragma unroll
            for (int j = 0; j < 4; ++j) acc[r][j] = bl[tc * 4 + j];
        int gr[4];
#pragma unroll
        for (int r = 0; r < 4; ++r) {
            int g = base + tr * 4 + r;
            gr[r] = (g < nNodes) ? g : 0;     // clamp; result never stored
        }
#pragma unroll
        for (int k4 = 0; k4 < 16; ++k4) {
            float4 A4[4], B4[4];
#pragma unroll
            for (int r = 0; r < 4; ++r) {
                if (ROOT_BF16) {
                    const ushort4 u4 = *(const ushort4*)&rootb[gr[r] * HIDDEN + k4 * 4];
                    A4[r].x = bf2f(u4.x); A4[r].y = bf2f(u4.y);
                    A4[r].z = bf2f(u4.z); A4[r].w = bf2f(u4.w);
                } else {
                    A4[r] = *(const float4*)&rootf[gr[r] * HIDDEN + k4 * 4];
                }
            }
#pragma unroll
            for (int kk = 0; kk < 4; ++kk)
                B4[kk] = *(const float4*)&sB[HIDDEN + k4 * 4 + kk][tc * 4];
#pragma unroll
            for (int r = 0; r < 4; ++r) {
                acc[r][0] = fmaf(A4[r].x, B4[0].x, acc[r][0]);
                acc[r][1] = fmaf(A4[r].x, B4[0].y, acc[r][1]);
                acc[r][2] = fmaf(A4[r].x, B4[0].z, acc[r][2]);
                acc[r][3] = fmaf(A4[r].x, B4[0].w, acc[r][3]);
                acc[r][0] = fmaf(A4[r].y, B4[1].x, acc[r][0]);
                acc[r][1] = fmaf(A4[r].y, B4[1].y, acc[r][1]);
                acc[r][2] = fmaf(A4[r].y, B4[1].z, acc[r][2]);
                acc[r][3] = fmaf(A4[r].y, B4[1].w, acc[r][3]);
                acc[r][0] = fmaf(A4[r].z, B4[2].x, acc[r][0]);
                acc[r][1] = fmaf(A4[r].z, B4[2].y, acc[r][1]);
                acc[r][2] = fmaf(A4[r].z, B4[2].z, acc[r][2]);
                acc[r][3] = fmaf(A4[r].z, B4[2].w, acc[r][3]);
                acc[r][0] = fmaf(A4[r].w, B4[3].x, acc[r][0]);
                acc[r][1] = fmaf(A4[r].w, B4[3].y, acc[r][1]);
                acc[r][2] = fmaf(A4[r].w, B4[3].z, acc[r][2]);
                acc[r][3] = fmaf(A4[r].w, B4[3].w, acc[r][3]);
            }
        }
    }
    __syncthreads();          // team0 done reading sM; repurpose as sC

    // ---- phase 5: combine + store ----
    if (team == 1) {
#pragma unroll
        for (int r = 0; r < 4; ++r) {
            float4 st;
            st.x = acc[r][0]; st.y = acc[r][1];
            st.z = acc[r][2]; st.w = acc[r][3];
            *(float4*)&sM[tr * 4 + r][tc * 4] = st;
        }
    }
    __syncthreads();
    if (team == 0) {
#pragma unroll
        for (int r = 0; r < 4; ++r) {
            const int g = base + tr * 4 + r;
            if (g < nNodes) {
                const float4 c4 = *(const float4*)&sM[tr * 4 + r][tc * 4];
                float4 o;
                o.x = acc[r][0] + c4.x; o.y = acc[r][1] + c4.y;
                o.z = acc[r][2] + c4.z; o.w = acc[r][3] + c4.w;
                if (RELU) {
                    o.x = fmaxf(o.x, 0.f); o.y = fmaxf(o.y, 0.f);
                    o.z = fmaxf(o.z, 0.f); o.w = fmaxf(o.w, 0.f);
                }
                if (OUT_BF16) {
                    ushort4 q;
                    q.x = f2bf(o.x); q.y = f2bf(o.y);
                    q.z = f2bf(o.z); q.w = f2bf(o.w);
                    *(ushort4*)&goutb[g * HIDDEN + tc * 4] = q;
                } else {
                    *(float4*)&outp[g * HIDDEN + tc * 4] = o;
                }
            }
        }
    }
}

extern "C" void kernel_launch(void* const* d_in, const int* in_sizes, int n_in,
                              void* d_out, int out_size, void* d_ws, size_t ws_size,
                              hipStream_t stream)
{
    const float* x   = (const float*)d_in[0];
    const int*   ei  = (const int*)d_in[1];   // [2,E]
    const float* W1l = (const float*)d_in[2];
    const float* b1l = (const float*)d_in[3];
    const float* W1r = (const float*)d_in[4];
    const float* W2l = (const float*)d_in[5];
    const float* b2l = (const float*)d_in[6];
    const float* W2r = (const float*)d_in[7];
    float* out = (float*)d_out;

    const int nNodes = in_sizes[0] / HIDDEN;   // 100000
    const int nEdges = in_sizes[1] / 2;        // 1250000

    // ws: cb2 [N*64 bf16] | deg [N+1] | rowPtr [N+1] | cursor [N] | csrSrc [E]
    //     | blockSum [512]                              (~19 MB total)
    // cb1 (bf16 of x) lives in d_out-as-scratch; overwritten by final output.
    unsigned short* cb2      = (unsigned short*)d_ws;
    int*            deg      = (int*)(cb2 + (size_t)nNodes * HIDDEN);
    int*            rowPtr   = deg + (nNodes + 1);
    int*            cursor   = rowPtr + (nNodes + 1);
    int*            csrSrc   = cursor + nNodes;
    int*            blockSum = csrSrc + nEdges;
    unsigned short* cb1      = (unsigned short*)d_out;

    const int nTiles  = (nNodes + TN - 1) / TN;
    const int nChunks = (nNodes + 255) / 256;
    const int nFeat8  = nNodes * HIDDEN / 8;

    // ---- CSR build (shared by both layers) ----
    hipMemsetAsync(deg, 0, (size_t)(nNodes + 1) * sizeof(int), stream);
    k_hist<<<2048, 256, 0, stream>>>(ei, deg, nEdges);
    k_scan1<<<nChunks, 256, 0, stream>>>(deg, rowPtr, blockSum, nNodes);
    k_scan2<<<1, 512, 0, stream>>>(blockSum, rowPtr, nChunks, nNodes);
    k_scan3<<<nChunks, 256, 0, stream>>>(rowPtr, cursor, blockSum, nNodes);
    k_fill<<<2048, 256, 0, stream>>>(ei, cursor, csrSrc, nEdges);

    // ---- layer 1: cb2 = bf16(relu(mean(x) @ W1l + b1l + x @ W1r)) ----
    k_tobf16<<<2048, 256, 0, stream>>>(x, cb1, nFeat8);
    k_fused<true, true, false><<<nTiles, 512, 0, stream>>>(
        cb1, x, nullptr, rowPtr, csrSrc, W1l, b1l, W1r, nullptr, cb2, nNodes);

    // ---- layer 2: out = mean(h) @ W2l + b2l + h @ W2r  (h = cb2, bf16) ----
    k_fused<false, false, true><<<nTiles, 512, 0, stream>>>(
        cb2, nullptr, cb2, rowPtr, csrSrc, W2l, b2l, W2r, out, nullptr, nNodes);
}